// Round 11
// baseline (457.481 us; speedup 1.0000x reference)
//
#include <hip/hip_runtime.h>
#include <stdint.h>

// GraphTransformerLayer MI355X: B=32 T=128 N=42 E=256 H=8 DH=32, f32 I/O.
// Round 11: split the monolith. The fused kernel was latency-bound at 8
// waves/CU (148 total regs > 128 -> 1 block/CU). Three kernels, each sized to
// its own register/occupancy budget:
//   wt_kernel:      W^T bf16 + dm8 table prepass (graph-constant)
//   qkv_kernel:     per graph: Q,K -> [g][48][256] bf16; V^T -> [g][256][48]
//   attn_wo_kernel: per graph: head/wave attention from global Q/K/VT + Wo GEMM

#define TPB 512
constexpr int BT = 4096;
constexpr int N = 42, NP = 48, E = 256, H = 8;
constexpr int NE = N * E;          // 10752
constexpr int NN = N * N;          // 1764
constexpr float SCALE = 0.17677669529663687f;  // 1/sqrt(32)

// ws layout (bytes)
constexpr size_t WT_OFF = 0;                                   // 524288
constexpr size_t DM_OFF = 524288;                              // 2304 (pad)
constexpr size_t Q_OFF  = 528384;                              // 100663296
constexpr size_t K_OFF  = Q_OFF + (size_t)BT * 48 * 256 * 2;   // 100663296
constexpr size_t VT_OFF = K_OFF + (size_t)BT * 48 * 256 * 2;   // 100663296
// total = 302,518,272 B

typedef short sh8 __attribute__((ext_vector_type(8)));   // 8 bf16
typedef float f4 __attribute__((ext_vector_type(4)));    // MFMA C/D frag

__device__ __forceinline__ uint32_t cvtpk(float lo, float hi) {
  uint32_t d;
  asm("v_cvt_pk_bf16_f32 %0, %1, %2" : "=v"(d) : "v"(lo), "v"(hi));
  return d;
}
__device__ __forceinline__ uint16_t f2b1(float f) { return (uint16_t)cvtpk(f, f); }
__device__ __forceinline__ float b2f(uint16_t u) {
  union { uint32_t i; float f; } v; v.i = ((uint32_t)u) << 16; return v.f;
}

// XOR swizzle for row-major bf16 [*][256] LDS tiles (512B row stride).
#define SWZ(base, row, cb) \
  ((char*)(base) + ((((row) << 9) + (cb)) ^ (((row) & 7) << 4)))

// ---- prepass: WT[n][k] = bf16(W[k][n]) x4, plus dm8 table -------------------
__global__ __launch_bounds__(256) void wt_kernel(
    const float* __restrict__ Wq, const float* __restrict__ Wk,
    const float* __restrict__ Wv, const float* __restrict__ Wo,
    const float* __restrict__ adj, const int* __restrict__ dist,
    uint16_t* __restrict__ WT, uint8_t* __restrict__ dm8g) {
  const int z = blockIdx.z;
  if (z == 4) {
    if (blockIdx.x == 0 && blockIdx.y == 0) {
      for (int t = threadIdx.x; t < NP * NP; t += 256) {
        const int i = t / NP, j = t - i * NP;
        uint8_t v = 0;
        if (i < N && j < N)
          v = (uint8_t)dist[i * N + j] | (adj[i * N + j] > 0.f ? 0x80 : 0);
        dm8g[t] = v;
      }
    }
    return;
  }
  __shared__ float tl[32][33];
  const float* W = (z == 0) ? Wq : (z == 1) ? Wk : (z == 2) ? Wv : Wo;
  uint16_t* dst = WT + z * 65536;
  const int k0 = blockIdx.y * 32, n0 = blockIdx.x * 32;
  const int r = threadIdx.x >> 5, cc = threadIdx.x & 31;
#pragma unroll
  for (int p = 0; p < 4; ++p)
    tl[r + 8 * p][cc] = W[(k0 + r + 8 * p) * E + n0 + cc];
  __syncthreads();
#pragma unroll
  for (int p = 0; p < 4; ++p)
    dst[(n0 + r + 8 * p) * E + k0 + cc] = f2b1(tl[cc][r + 8 * p]);
}

// one GEMM pass: acc[mt][nt] = Xb(swz) @ Wt^T tiles (wave cols nt0..nt0+1)
__device__ __forceinline__ void gemm_pass(const uint16_t* __restrict__ Wt,
                                          const char* Xb, int c, int lg, int nt0,
                                          f4 acc[3][2]) {
#pragma unroll
  for (int mt = 0; mt < 3; ++mt)
#pragma unroll
    for (int nt = 0; nt < 2; ++nt) acc[mt][nt] = (f4){0.f, 0.f, 0.f, 0.f};
  for (int kc = 0; kc < E; kc += 32) {
    sh8 xa[3];
#pragma unroll
    for (int mt = 0; mt < 3; ++mt)
      xa[mt] = *(const sh8*)SWZ(Xb, 16 * mt + c, (kc + 8 * lg) * 2);
#pragma unroll
    for (int nt = 0; nt < 2; ++nt) {
      const sh8 b8 = *(const sh8*)(Wt + ((nt0 + nt) * 16 + c) * E + kc + 8 * lg);
#pragma unroll
      for (int mt = 0; mt < 3; ++mt)
        acc[mt][nt] = __builtin_amdgcn_mfma_f32_16x16x32_bf16(xa[mt], b8, acc[mt][nt], 0, 0, 0);
    }
  }
}

// ---- K1: QKV GEMM -> Qg, Kg ([g][48][256] bf16), VTg ([g][256][48] bf16) ----
__global__ __launch_bounds__(TPB, 4) void qkv_kernel(
    const float* __restrict__ X,
    const float* __restrict__ bq, const float* __restrict__ bk,
    const float* __restrict__ bv, const uint16_t* __restrict__ WT,
    uint16_t* __restrict__ Qg, uint16_t* __restrict__ Kg,
    char* __restrict__ VTg) {
  alignas(16) __shared__ char Xb[NP * 512];  // 24576 B
  const int gid = blockIdx.x;
  const int tid = threadIdx.x;
  const int w = tid >> 6, lane = tid & 63, c = lane & 15, lg = lane >> 4;
  const int nt0 = 2 * w, n0 = 32 * w;

  // stage X (f32->bf16, swizzled) + full pad rows
  {
    const float4* Xs = (const float4*)(X + (size_t)gid * NE);
    for (int i = tid; i < NE / 4; i += TPB) {
      const float4 v = Xs[i];
      uint2 pk; pk.x = cvtpk(v.x, v.y); pk.y = cvtpk(v.z, v.w);
      *(uint2*)SWZ(Xb, i >> 6, (i & 63) << 3) = pk;
    }
    for (int i = tid; i < (NP - N) * 64; i += TPB) {
      uint2 z; z.x = 0u; z.y = 0u;
      *(uint2*)SWZ(Xb, N + (i >> 6), (i & 63) << 3) = z;
    }
  }
  __syncthreads();

  f4 acc[3][2];
  // Q
  gemm_pass(WT, Xb, c, lg, nt0, acc);
#pragma unroll
  for (int nt = 0; nt < 2; ++nt) {
    const int n = n0 + 16 * nt + c;
    const float bv_ = bq[n];
#pragma unroll
    for (int mt = 0; mt < 3; ++mt)
#pragma unroll
      for (int r = 0; r < 4; ++r) {
        const int i = 16 * mt + 4 * lg + r;
        Qg[((size_t)gid * 48 + i) * 256 + n] = f2b1(acc[mt][nt][r] + bv_);
      }
  }
  // K
  gemm_pass(WT + 65536, Xb, c, lg, nt0, acc);
#pragma unroll
  for (int nt = 0; nt < 2; ++nt) {
    const int n = n0 + 16 * nt + c;
    const float bv_ = bk[n];
#pragma unroll
    for (int mt = 0; mt < 3; ++mt)
#pragma unroll
      for (int r = 0; r < 4; ++r) {
        const int i = 16 * mt + 4 * lg + r;
        Kg[((size_t)gid * 48 + i) * 256 + n] = f2b1(acc[mt][nt][r] + bv_);
      }
  }
  // V -> transposed [256][48]
  gemm_pass(WT + 131072, Xb, c, lg, nt0, acc);
  char* const vt = VTg + (size_t)gid * 24576;
#pragma unroll
  for (int nt = 0; nt < 2; ++nt) {
    const int n = n0 + 16 * nt + c;
    const float bv_ = bv[n];
#pragma unroll
    for (int mt = 0; mt < 3; ++mt) {
      uint2 pk;
      pk.x = cvtpk(acc[mt][nt][0] + bv_, acc[mt][nt][1] + bv_);
      pk.y = cvtpk(acc[mt][nt][2] + bv_, acc[mt][nt][3] + bv_);
      *(uint2*)(vt + n * 96 + 32 * mt + 8 * lg) = pk;
    }
  }
}

// ---- K2: attention (head = wave) + Wo GEMM ----------------------------------
// LDS (70368 B -> 2 blocks/CU):
//  [0,24576)      Ob: O swz [48][256] bf16
//  [24576,67584)  per-wave 5376 B: Ps [48][56] bf16
//  [67584,69888)  dm8;  [69888,70368) relL
__global__ __launch_bounds__(TPB, 4) void attn_wo_kernel(
    const float* __restrict__ bo, const float* __restrict__ rel,
    const uint16_t* __restrict__ WT, const uint16_t* __restrict__ Qg,
    const uint16_t* __restrict__ Kg, const char* __restrict__ VTg,
    const uint8_t* __restrict__ dm8g,
    float* __restrict__ out, float* __restrict__ attn) {
  alignas(16) __shared__ char smem[70368];
  char* const Ob = smem;
  uint8_t* const dm8 = (uint8_t*)(smem + 67584);
  float*   const relL = (float*)(smem + 69888);

  const int gid = blockIdx.x;
  const int tid = threadIdx.x;
  const int w = tid >> 6, lane = tid & 63, c = lane & 15, lg = lane >> 4;
  const int nt0 = 2 * w, n0 = 32 * w, h = w;
  uint16_t* const scr = (uint16_t*)(smem + 24576 + w * 5376);  // wave-private

  for (int t = tid; t < NP * NP; t += TPB) dm8[t] = dm8g[t];
  for (int t = tid; t < 120; t += TPB) relL[t] = rel[t];
  __syncthreads();  // b1

  // Q/K fragments straight from global (rows 16mt+c, cols 32h+8lg..)
  sh8 qa[3], kb[3];
#pragma unroll
  for (int mt = 0; mt < 3; ++mt) {
    const size_t ro = ((size_t)gid * 48 + 16 * mt + c) * 256 + 32 * h + 8 * lg;
    qa[mt] = *(const sh8*)(Qg + ro);
    kb[mt] = *(const sh8*)(Kg + ro);
  }

  f4 st[3][3];
#pragma unroll
  for (int mt = 0; mt < 3; ++mt)
#pragma unroll
    for (int nt = 0; nt < 3; ++nt) {
      st[mt][nt] = (f4){0.f, 0.f, 0.f, 0.f};
      st[mt][nt] = __builtin_amdgcn_mfma_f32_16x16x32_bf16(kb[mt], qa[nt], st[mt][nt], 0, 0, 0);
    }
  // lane (lg,c) reg r of st[mt][nt]: score[i=16nt+c][j=16mt+4lg+r]

  uint16_t* const Psw = scr;  // [48][56] bf16
#pragma unroll
  for (int nt = 0; nt < 3; ++nt) {
    const int i = 16 * nt + c;
    float sv[12];
#pragma unroll
    for (int mt = 0; mt < 3; ++mt)
#pragma unroll
      for (int r = 0; r < 4; ++r) {
        const int j = 16 * mt + 4 * lg + r;
        const uint8_t dm = dm8[i * NP + j];
        const float s = st[mt][nt][r] * SCALE + relL[(dm & 0x7f) * 8 + h];
        sv[mt * 4 + r] = (dm & 0x80) ? s : -1e9f;
      }
    float m = sv[0];
#pragma unroll
    for (int k = 1; k < 12; ++k) m = fmaxf(m, sv[k]);
    m = fmaxf(m, __shfl_xor(m, 16));
    m = fmaxf(m, __shfl_xor(m, 32));
    float p[12], sum = 0.f;
#pragma unroll
    for (int k = 0; k < 12; ++k) { p[k] = __expf(sv[k] - m); sum += p[k]; }
    sum += __shfl_xor(sum, 16);
    sum += __shfl_xor(sum, 32);
    const float inv = __builtin_amdgcn_rcpf(sum);
#pragma unroll
    for (int mt = 0; mt < 3; ++mt) {
      const uint32_t d0 = cvtpk(p[mt * 4 + 0] * inv, p[mt * 4 + 1] * inv);
      const uint32_t d1 = cvtpk(p[mt * 4 + 2] * inv, p[mt * 4 + 3] * inv);
      char* base = (char*)Psw + i * 112 + 32 * mt + 8 * lg;
      *(uint32_t*)base = d0;
      *(uint32_t*)(base + 4) = d1;
    }
  }

  // coalesced attn store from Psw (wave-private region)
  {
    const size_t abase = ((size_t)gid * H + h) * (size_t)NN;
    for (int p = lane; p < NN; p += 64) {
      const int i = p / N, j = p - i * N;
      attn[abase + p] = b2f(Psw[i * 56 + j]);
    }
  }

  // PV: O_h = P @ V_h  (A = P rows from Psw, B = V^T rows from global VTg)
  const sh8 z8 = {0, 0, 0, 0, 0, 0, 0, 0};
  sh8 pa0[3], pa1[3], vb0[2], vb1[2];
#pragma unroll
  for (int mt = 0; mt < 3; ++mt) {
    char* base = (char*)Psw + (16 * mt + c) * 112;
    pa0[mt] = *(const sh8*)(base + 16 * lg);
    pa1[mt] = (lg < 2) ? *(const sh8*)(base + 64 + 16 * lg) : z8;
  }
#pragma unroll
  for (int nt = 0; nt < 2; ++nt) {
    const char* base = VTg + (size_t)gid * 24576 + (h * 32 + 16 * nt + c) * 96;
    vb0[nt] = *(const sh8*)(base + 16 * lg);
    vb1[nt] = (lg < 2) ? *(const sh8*)(base + 64 + 16 * lg) : z8;
  }
  f4 ov[3][2];
#pragma unroll
  for (int mt = 0; mt < 3; ++mt)
#pragma unroll
    for (int nt = 0; nt < 2; ++nt) {
      ov[mt][nt] = (f4){0.f, 0.f, 0.f, 0.f};
      ov[mt][nt] = __builtin_amdgcn_mfma_f32_16x16x32_bf16(pa0[mt], vb0[nt], ov[mt][nt], 0, 0, 0);
      ov[mt][nt] = __builtin_amdgcn_mfma_f32_16x16x32_bf16(pa1[mt], vb1[nt], ov[mt][nt], 0, 0, 0);
    }

  // O -> swizzled LDS (fresh region, no prior use -> no barrier needed before)
#pragma unroll
  for (int mt = 0; mt < 3; ++mt)
#pragma unroll
    for (int nt = 0; nt < 2; ++nt)
#pragma unroll
      for (int r = 0; r < 4; ++r)
        *(uint16_t*)SWZ(Ob, 16 * mt + 4 * lg + r, (n0 + 16 * nt + c) * 2) =
            f2b1(ov[mt][nt][r]);
  __syncthreads();  // b2: O complete

  // Wo GEMM: out = O @ Wo + bo
  {
    f4 ao[3][2];
    gemm_pass(WT + 196608, Ob, c, lg, nt0, ao);
#pragma unroll
    for (int nt = 0; nt < 2; ++nt) {
      const int n = n0 + 16 * nt + c;
      const float bov = bo[n];
#pragma unroll
      for (int mt = 0; mt < 3; ++mt)
#pragma unroll
        for (int r = 0; r < 4; ++r) {
          const int i = 16 * mt + 4 * lg + r;
          if (i < N) out[(size_t)gid * NE + i * E + n] = ao[mt][nt][r] + bov;
        }
    }
  }
}

extern "C" void kernel_launch(void* const* d_in, const int* in_sizes, int n_in,
                              void* d_out, int out_size, void* d_ws, size_t ws_size,
                              hipStream_t stream) {
  const float* X    = (const float*)d_in[0];
  const float* adj  = (const float*)d_in[1];
  const int*   dist = (const int*)d_in[2];
  const float* Wq   = (const float*)d_in[3];
  const float* bq   = (const float*)d_in[4];
  const float* Wk   = (const float*)d_in[5];
  const float* bk   = (const float*)d_in[6];
  const float* Wv   = (const float*)d_in[7];
  const float* bv   = (const float*)d_in[8];
  const float* Wo   = (const float*)d_in[9];
  const float* bo   = (const float*)d_in[10];
  const float* rel  = (const float*)d_in[11];
  float* out  = (float*)d_out;
  float* attn = out + (size_t)BT * NE;

  char* ws = (char*)d_ws;
  uint16_t* WT   = (uint16_t*)(ws + WT_OFF);
  uint8_t*  dm8g = (uint8_t*)(ws + DM_OFF);
  uint16_t* Qg   = (uint16_t*)(ws + Q_OFF);
  uint16_t* Kg   = (uint16_t*)(ws + K_OFF);
  char*     VTg  = ws + VT_OFF;

  wt_kernel<<<dim3(8, 8, 5), dim3(256), 0, stream>>>(Wq, Wk, Wv, Wo, adj, dist, WT, dm8g);
  qkv_kernel<<<dim3(BT), dim3(TPB), 0, stream>>>(X, bq, bk, bv, WT, Qg, Kg, VTg);
  attn_wo_kernel<<<dim3(BT), dim3(TPB), 0, stream>>>(bo, rel, WT, Qg, Kg, VTg, dm8g, out, attn);
}

// Round 12
// 441.283 us; speedup vs baseline: 1.0367x; 1.0367x over previous
//
#include <hip/hip_runtime.h>
#include <stdint.h>

// GraphTransformerLayer MI355X: B=32 T=128 N=42 E=256 H=8 DH=32, f32 I/O.
// Round 12: round-11 split + qkv store coalescing. qkv was 278us (3.7x BW
// floor) from scalar 2B global stores (9.2M sub-64B segments). Fix: stage
// Q/K/VT epilogues in LDS, copy out coalesced (16B/lane), with copy-out of
// matrix i overlapped with GEMM of matrix i+1.

#define TPB 512
constexpr int BT = 4096;
constexpr int N = 42, NP = 48, E = 256, H = 8;
constexpr int NE = N * E;          // 10752
constexpr int NN = N * N;          // 1764
constexpr float SCALE = 0.17677669529663687f;  // 1/sqrt(32)

// ws layout (bytes)
constexpr size_t WT_OFF = 0;                                   // 524288
constexpr size_t DM_OFF = 524288;                              // 2304 (pad)
constexpr size_t Q_OFF  = 528384;
constexpr size_t K_OFF  = Q_OFF + (size_t)BT * 48 * 256 * 2;
constexpr size_t VT_OFF = K_OFF + (size_t)BT * 48 * 256 * 2;
// total = 302,518,272 B

typedef short sh8 __attribute__((ext_vector_type(8)));   // 8 bf16
typedef float f4 __attribute__((ext_vector_type(4)));    // MFMA C/D frag

__device__ __forceinline__ uint32_t cvtpk(float lo, float hi) {
  uint32_t d;
  asm("v_cvt_pk_bf16_f32 %0, %1, %2" : "=v"(d) : "v"(lo), "v"(hi));
  return d;
}
__device__ __forceinline__ uint16_t f2b1(float f) { return (uint16_t)cvtpk(f, f); }
__device__ __forceinline__ float b2f(uint16_t u) {
  union { uint32_t i; float f; } v; v.i = ((uint32_t)u) << 16; return v.f;
}

// XOR swizzle for row-major bf16 [*][256] LDS tiles (512B row stride).
#define SWZ(base, row, cb) \
  ((char*)(base) + ((((row) << 9) + (cb)) ^ (((row) & 7) << 4)))

// ---- prepass: WT[n][k] = bf16(W[k][n]) x4, plus dm8 table -------------------
__global__ __launch_bounds__(256) void wt_kernel(
    const float* __restrict__ Wq, const float* __restrict__ Wk,
    const float* __restrict__ Wv, const float* __restrict__ Wo,
    const float* __restrict__ adj, const int* __restrict__ dist,
    uint16_t* __restrict__ WT, uint8_t* __restrict__ dm8g) {
  const int z = blockIdx.z;
  if (z == 4) {
    if (blockIdx.x == 0 && blockIdx.y == 0) {
      for (int t = threadIdx.x; t < NP * NP; t += 256) {
        const int i = t / NP, j = t - i * NP;
        uint8_t v = 0;
        if (i < N && j < N)
          v = (uint8_t)dist[i * N + j] | (adj[i * N + j] > 0.f ? 0x80 : 0);
        dm8g[t] = v;
      }
    }
    return;
  }
  __shared__ float tl[32][33];
  const float* W = (z == 0) ? Wq : (z == 1) ? Wk : (z == 2) ? Wv : Wo;
  uint16_t* dst = WT + z * 65536;
  const int k0 = blockIdx.y * 32, n0 = blockIdx.x * 32;
  const int r = threadIdx.x >> 5, cc = threadIdx.x & 31;
#pragma unroll
  for (int p = 0; p < 4; ++p)
    tl[r + 8 * p][cc] = W[(k0 + r + 8 * p) * E + n0 + cc];
  __syncthreads();
#pragma unroll
  for (int p = 0; p < 4; ++p)
    dst[(n0 + r + 8 * p) * E + k0 + cc] = f2b1(tl[cc][r + 8 * p]);
}

// one GEMM pass: acc[mt][nt] = Xb(swz) @ Wt^T tiles (wave cols nt0..nt0+1)
__device__ __forceinline__ void gemm_pass(const uint16_t* __restrict__ Wt,
                                          const char* Xb, int c, int lg, int nt0,
                                          f4 acc[3][2]) {
#pragma unroll
  for (int mt = 0; mt < 3; ++mt)
#pragma unroll
    for (int nt = 0; nt < 2; ++nt) acc[mt][nt] = (f4){0.f, 0.f, 0.f, 0.f};
  for (int kc = 0; kc < E; kc += 32) {
    sh8 xa[3];
#pragma unroll
    for (int mt = 0; mt < 3; ++mt)
      xa[mt] = *(const sh8*)SWZ(Xb, 16 * mt + c, (kc + 8 * lg) * 2);
#pragma unroll
    for (int nt = 0; nt < 2; ++nt) {
      const sh8 b8 = *(const sh8*)(Wt + ((nt0 + nt) * 16 + c) * E + kc + 8 * lg);
#pragma unroll
      for (int mt = 0; mt < 3; ++mt)
        acc[mt][nt] = __builtin_amdgcn_mfma_f32_16x16x32_bf16(xa[mt], b8, acc[mt][nt], 0, 0, 0);
    }
  }
}

// Q/K epilogue: C-frags + bias -> LDS stage [48][256] bf16 (linear)
__device__ __forceinline__ void frag_to_stage(const f4 acc[3][2],
                                              const float* __restrict__ bias,
                                              int n0, int c, int lg,
                                              uint16_t* __restrict__ stage) {
#pragma unroll
  for (int nt = 0; nt < 2; ++nt) {
    const int n = n0 + 16 * nt + c;
    const float bv_ = bias[n];
#pragma unroll
    for (int mt = 0; mt < 3; ++mt)
#pragma unroll
      for (int r = 0; r < 4; ++r)
        stage[(16 * mt + 4 * lg + r) * 256 + n] = f2b1(acc[mt][nt][r] + bv_);
  }
}

// ---- K1: QKV GEMM -> Qg, Kg ([g][48][256] bf16), VTg ([g][256][48] bf16) ----
__global__ __launch_bounds__(TPB, 4) void qkv_kernel(
    const float* __restrict__ X,
    const float* __restrict__ bq, const float* __restrict__ bk,
    const float* __restrict__ bv, const uint16_t* __restrict__ WT,
    uint16_t* __restrict__ Qg, uint16_t* __restrict__ Kg,
    char* __restrict__ VTg) {
  alignas(16) __shared__ char Xb[NP * 512];      // 24576 B
  alignas(16) __shared__ char stage[NP * 512];   // 24576 B, reused Q->K->VT
  const int gid = blockIdx.x;
  const int tid = threadIdx.x;
  const int w = tid >> 6, lane = tid & 63, c = lane & 15, lg = lane >> 4;
  const int nt0 = 2 * w, n0 = 32 * w;

  // stage X (f32->bf16, swizzled) + full pad rows
  {
    const float4* Xs = (const float4*)(X + (size_t)gid * NE);
    for (int i = tid; i < NE / 4; i += TPB) {
      const float4 v = Xs[i];
      uint2 pk; pk.x = cvtpk(v.x, v.y); pk.y = cvtpk(v.z, v.w);
      *(uint2*)SWZ(Xb, i >> 6, (i & 63) << 3) = pk;
    }
    for (int i = tid; i < (NP - N) * 64; i += TPB) {
      uint2 z; z.x = 0u; z.y = 0u;
      *(uint2*)SWZ(Xb, N + (i >> 6), (i & 63) << 3) = z;
    }
  }
  __syncthreads();  // b1

  f4 acc[3][2];
  // ---- Q ----
  gemm_pass(WT, Xb, c, lg, nt0, acc);
  frag_to_stage(acc, bq, n0, c, lg, (uint16_t*)stage);
  __syncthreads();  // b2: stage complete
  // copy Q out (coalesced) overlapped with K GEMM
  {
    uint4* dst = (uint4*)(Qg + (size_t)gid * 12288);
    const uint4* src = (const uint4*)stage;
    for (int i = tid; i < 1536; i += TPB) dst[i] = src[i];
  }
  gemm_pass(WT + 65536, Xb, c, lg, nt0, acc);
  __syncthreads();  // b3: all copy reads of stage done
  frag_to_stage(acc, bk, n0, c, lg, (uint16_t*)stage);
  __syncthreads();  // b4: stage complete
  // copy K out overlapped with V GEMM
  {
    uint4* dst = (uint4*)(Kg + (size_t)gid * 12288);
    const uint4* src = (const uint4*)stage;
    for (int i = tid; i < 1536; i += TPB) dst[i] = src[i];
  }
  gemm_pass(WT + 131072, Xb, c, lg, nt0, acc);
  __syncthreads();  // b5: all copy reads of stage done
  // V -> transposed [256][48] bf16 into stage
#pragma unroll
  for (int nt = 0; nt < 2; ++nt) {
    const int n = n0 + 16 * nt + c;
    const float bv_ = bv[n];
#pragma unroll
    for (int mt = 0; mt < 3; ++mt) {
      uint2 pk;
      pk.x = cvtpk(acc[mt][nt][0] + bv_, acc[mt][nt][1] + bv_);
      pk.y = cvtpk(acc[mt][nt][2] + bv_, acc[mt][nt][3] + bv_);
      *(uint2*)(stage + n * 96 + 32 * mt + 8 * lg) = pk;
    }
  }
  __syncthreads();  // b6: stage complete
  {
    uint4* dst = (uint4*)(VTg + (size_t)gid * 24576);
    const uint4* src = (const uint4*)stage;
    for (int i = tid; i < 1536; i += TPB) dst[i] = src[i];
  }
}

// ---- K2: attention (head = wave) + Wo GEMM ----------------------------------
// LDS (70368 B):
//  [0,24576)      Ob: O swz [48][256] bf16
//  [24576,67584)  per-wave 5376 B: Ps [48][56] bf16
//  [67584,69888)  dm8;  [69888,70368) relL
__global__ __launch_bounds__(TPB, 4) void attn_wo_kernel(
    const float* __restrict__ bo, const float* __restrict__ rel,
    const uint16_t* __restrict__ WT, const uint16_t* __restrict__ Qg,
    const uint16_t* __restrict__ Kg, const char* __restrict__ VTg,
    const uint8_t* __restrict__ dm8g,
    float* __restrict__ out, float* __restrict__ attn) {
  alignas(16) __shared__ char smem[70368];
  char* const Ob = smem;
  uint8_t* const dm8 = (uint8_t*)(smem + 67584);
  float*   const relL = (float*)(smem + 69888);

  const int gid = blockIdx.x;
  const int tid = threadIdx.x;
  const int w = tid >> 6, lane = tid & 63, c = lane & 15, lg = lane >> 4;
  const int nt0 = 2 * w, n0 = 32 * w, h = w;
  uint16_t* const scr = (uint16_t*)(smem + 24576 + w * 5376);  // wave-private

  for (int t = tid; t < NP * NP; t += TPB) dm8[t] = dm8g[t];
  for (int t = tid; t < 120; t += TPB) relL[t] = rel[t];
  __syncthreads();  // b1

  // Q/K fragments straight from global (rows 16mt+c, cols 32h+8lg..)
  sh8 qa[3], kb[3];
#pragma unroll
  for (int mt = 0; mt < 3; ++mt) {
    const size_t ro = ((size_t)gid * 48 + 16 * mt + c) * 256 + 32 * h + 8 * lg;
    qa[mt] = *(const sh8*)(Qg + ro);
    kb[mt] = *(const sh8*)(Kg + ro);
  }

  f4 st[3][3];
#pragma unroll
  for (int mt = 0; mt < 3; ++mt)
#pragma unroll
    for (int nt = 0; nt < 3; ++nt) {
      st[mt][nt] = (f4){0.f, 0.f, 0.f, 0.f};
      st[mt][nt] = __builtin_amdgcn_mfma_f32_16x16x32_bf16(kb[mt], qa[nt], st[mt][nt], 0, 0, 0);
    }
  // lane (lg,c) reg r of st[mt][nt]: score[i=16nt+c][j=16mt+4lg+r]

  uint16_t* const Psw = scr;  // [48][56] bf16
#pragma unroll
  for (int nt = 0; nt < 3; ++nt) {
    const int i = 16 * nt + c;
    float sv[12];
#pragma unroll
    for (int mt = 0; mt < 3; ++mt)
#pragma unroll
      for (int r = 0; r < 4; ++r) {
        const int j = 16 * mt + 4 * lg + r;
        const uint8_t dm = dm8[i * NP + j];
        const float s = st[mt][nt][r] * SCALE + relL[(dm & 0x7f) * 8 + h];
        sv[mt * 4 + r] = (dm & 0x80) ? s : -1e9f;
      }
    float m = sv[0];
#pragma unroll
    for (int k = 1; k < 12; ++k) m = fmaxf(m, sv[k]);
    m = fmaxf(m, __shfl_xor(m, 16));
    m = fmaxf(m, __shfl_xor(m, 32));
    float p[12], sum = 0.f;
#pragma unroll
    for (int k = 0; k < 12; ++k) { p[k] = __expf(sv[k] - m); sum += p[k]; }
    sum += __shfl_xor(sum, 16);
    sum += __shfl_xor(sum, 32);
    const float inv = __builtin_amdgcn_rcpf(sum);
#pragma unroll
    for (int mt = 0; mt < 3; ++mt) {
      const uint32_t d0 = cvtpk(p[mt * 4 + 0] * inv, p[mt * 4 + 1] * inv);
      const uint32_t d1 = cvtpk(p[mt * 4 + 2] * inv, p[mt * 4 + 3] * inv);
      char* base = (char*)Psw + i * 112 + 32 * mt + 8 * lg;
      *(uint32_t*)base = d0;
      *(uint32_t*)(base + 4) = d1;
    }
  }

  // coalesced attn store from Psw (wave-private region)
  {
    const size_t abase = ((size_t)gid * H + h) * (size_t)NN;
    for (int p = lane; p < NN; p += 64) {
      const int i = p / N, j = p - i * N;
      attn[abase + p] = b2f(Psw[i * 56 + j]);
    }
  }

  // PV: O_h = P @ V_h  (A = P rows from Psw, B = V^T rows from global VTg)
  const sh8 z8 = {0, 0, 0, 0, 0, 0, 0, 0};
  sh8 pa0[3], pa1[3], vb0[2], vb1[2];
#pragma unroll
  for (int mt = 0; mt < 3; ++mt) {
    char* base = (char*)Psw + (16 * mt + c) * 112;
    pa0[mt] = *(const sh8*)(base + 16 * lg);
    pa1[mt] = (lg < 2) ? *(const sh8*)(base + 64 + 16 * lg) : z8;
  }
#pragma unroll
  for (int nt = 0; nt < 2; ++nt) {
    const char* base = VTg + (size_t)gid * 24576 + (h * 32 + 16 * nt + c) * 96;
    vb0[nt] = *(const sh8*)(base + 16 * lg);
    vb1[nt] = (lg < 2) ? *(const sh8*)(base + 64 + 16 * lg) : z8;
  }
  f4 ov[3][2];
#pragma unroll
  for (int mt = 0; mt < 3; ++mt)
#pragma unroll
    for (int nt = 0; nt < 2; ++nt) {
      ov[mt][nt] = (f4){0.f, 0.f, 0.f, 0.f};
      ov[mt][nt] = __builtin_amdgcn_mfma_f32_16x16x32_bf16(pa0[mt], vb0[nt], ov[mt][nt], 0, 0, 0);
      ov[mt][nt] = __builtin_amdgcn_mfma_f32_16x16x32_bf16(pa1[mt], vb1[nt], ov[mt][nt], 0, 0, 0);
    }

  // O -> swizzled LDS (fresh region)
#pragma unroll
  for (int mt = 0; mt < 3; ++mt)
#pragma unroll
    for (int nt = 0; nt < 2; ++nt)
#pragma unroll
      for (int r = 0; r < 4; ++r)
        *(uint16_t*)SWZ(Ob, 16 * mt + 4 * lg + r, (n0 + 16 * nt + c) * 2) =
            f2b1(ov[mt][nt][r]);
  __syncthreads();  // b2: O complete

  // Wo GEMM: out = O @ Wo + bo
  {
    f4 ao[3][2];
    gemm_pass(WT + 196608, Ob, c, lg, nt0, ao);
#pragma unroll
    for (int nt = 0; nt < 2; ++nt) {
      const int n = n0 + 16 * nt + c;
      const float bov = bo[n];
#pragma unroll
      for (int mt = 0; mt < 3; ++mt)
#pragma unroll
        for (int r = 0; r < 4; ++r) {
          const int i = 16 * mt + 4 * lg + r;
          if (i < N) out[(size_t)gid * NE + i * E + n] = ao[mt][nt][r] + bov;
        }
    }
  }
}

extern "C" void kernel_launch(void* const* d_in, const int* in_sizes, int n_in,
                              void* d_out, int out_size, void* d_ws, size_t ws_size,
                              hipStream_t stream) {
  const float* X    = (const float*)d_in[0];
  const float* adj  = (const float*)d_in[1];
  const int*   dist = (const int*)d_in[2];
  const float* Wq   = (const float*)d_in[3];
  const float* bq   = (const float*)d_in[4];
  const float* Wk   = (const float*)d_in[5];
  const float* bk   = (const float*)d_in[6];
  const float* Wv   = (const float*)d_in[7];
  const float* bv   = (const float*)d_in[8];
  const float* Wo   = (const float*)d_in[9];
  const float* bo   = (const float*)d_in[10];
  const float* rel  = (const float*)d_in[11];
  float* out  = (float*)d_out;
  float* attn = out + (size_t)BT * NE;

  char* ws = (char*)d_ws;
  uint16_t* WT   = (uint16_t*)(ws + WT_OFF);
  uint8_t*  dm8g = (uint8_t*)(ws + DM_OFF);
  uint16_t* Qg   = (uint16_t*)(ws + Q_OFF);
  uint16_t* Kg   = (uint16_t*)(ws + K_OFF);
  char*     VTg  = ws + VT_OFF;

  wt_kernel<<<dim3(8, 8, 5), dim3(256), 0, stream>>>(Wq, Wk, Wv, Wo, adj, dist, WT, dm8g);
  qkv_kernel<<<dim3(BT), dim3(TPB), 0, stream>>>(X, bq, bk, bv, WT, Qg, Kg, VTg);
  attn_wo_kernel<<<dim3(BT), dim3(TPB), 0, stream>>>(bo, rel, WT, Qg, Kg, VTg, dm8g, out, attn);
}